// Round 1
// baseline (258.007 us; speedup 1.0000x reference)
//
#include <hip/hip_runtime.h>

#define B_ 2
#define S_ 2048
#define E_ 1024
#define H_ 16
#define D_ 64

typedef short  s16x8 __attribute__((ext_vector_type(8)));
typedef float  f32x4 __attribute__((ext_vector_type(4)));
typedef unsigned short u16x4 __attribute__((ext_vector_type(4)));

__device__ __forceinline__ ushort f2bf(float f) {
    union { float f; unsigned u; } x; x.f = f;
    unsigned u = x.u + 0x7fffu + ((x.u >> 16) & 1u);   // RNE
    return (ushort)(u >> 16);
}

// ---------------------------------------------------------------------------
// X fp32 -> bf16 (flat, 4 elems/thread)
// ---------------------------------------------------------------------------
__global__ __launch_bounds__(256) void cvtx_kernel(
    const float* __restrict__ X, ushort* __restrict__ Xbf)
{
    int i = (blockIdx.x * 256 + threadIdx.x) * 4;
    float4 v = *(const float4*)&X[i];
    u16x4 o;
    o.x = f2bf(v.x); o.y = f2bf(v.y); o.z = f2bf(v.z); o.w = f2bf(v.w);
    *(u16x4*)&Xbf[i] = o;
}

// ---------------------------------------------------------------------------
// W fp32 [Kdim][Ndim] -> Wt bf16 [Ndim][Kdim]  (64x64 LDS tiles)
// ---------------------------------------------------------------------------
__global__ __launch_bounds__(256) void wtrans_kernel(
    const float* __restrict__ W, ushort* __restrict__ Wt, int Kdim, int Ndim)
{
    __shared__ float tile[64][65];
    int n0 = blockIdx.x * 64, k0 = blockIdx.y * 64;
    int tid = threadIdx.x;
    int c = tid & 63;
#pragma unroll
    for (int r = tid >> 6; r < 64; r += 4)
        tile[r][c] = W[(size_t)(k0 + r) * Ndim + n0 + c];
    __syncthreads();
#pragma unroll
    for (int r = tid >> 6; r < 64; r += 4)
        Wt[(size_t)(n0 + r) * Kdim + k0 + c] = f2bf(tile[c][r]);
}

// ---------------------------------------------------------------------------
// bf16 MFMA GEMM (m97 structure): C[m][n] = sum_k A[m][k]*Bt[n][k] + bias[n]
// 128x128 tile, BK=32, global_load_lds w=16, ds_read_b128 frags.
// mode 0: fp32 C0. mode 1 (N=3E): seg0->Qbf, seg1->Kf32+Kbf, seg2->Vf32.
// ---------------------------------------------------------------------------
__global__ __launch_bounds__(256) void gemm_mfma_bt(
    const ushort* __restrict__ A,    // [M][K] bf16
    const ushort* __restrict__ Bt,   // [N][K] bf16
    const float* __restrict__ bias,  // [N]
    int M, int N, int K,
    float* __restrict__ C0,
    ushort* __restrict__ Qbf, float* __restrict__ Kf32, ushort* __restrict__ Kbf,
    float* __restrict__ Vf32, int mode)
{
    __shared__ ushort As[128 * 32];
    __shared__ ushort Bs[128 * 32];
    int tid = threadIdx.x;
    int wid = tid >> 6, lane = tid & 63;
    int l15 = lane & 15, quad = lane >> 4;
    int wm = wid >> 1, wn = wid & 1;
    int row0 = blockIdx.y * 128, col0 = blockIdx.x * 128;

    int sr = wid * 16 + (lane >> 2);
    int sk = (lane & 3) * 8;

    f32x4 acc[4][4];
#pragma unroll
    for (int mt = 0; mt < 4; mt++)
#pragma unroll
        for (int nt = 0; nt < 4; nt++) acc[mt][nt] = (f32x4){0.f, 0.f, 0.f, 0.f};

    for (int k0 = 0; k0 < K; k0 += 32) {
        __syncthreads();
#pragma unroll
        for (int c = 0; c < 2; c++) {
            int r = c * 64 + sr;
            __builtin_amdgcn_global_load_lds(
                (const __attribute__((address_space(1))) unsigned int*)
                    &A[(size_t)(row0 + r) * K + k0 + sk],
                (__attribute__((address_space(3))) unsigned int*)&As[r * 32 + sk],
                16, 0, 0);
            __builtin_amdgcn_global_load_lds(
                (const __attribute__((address_space(1))) unsigned int*)
                    &Bt[(size_t)(col0 + r) * K + k0 + sk],
                (__attribute__((address_space(3))) unsigned int*)&Bs[r * 32 + sk],
                16, 0, 0);
        }
        __syncthreads();

        s16x8 af[4], bf[4];
#pragma unroll
        for (int mt = 0; mt < 4; mt++)
            af[mt] = *(const s16x8*)&As[(wm * 64 + mt * 16 + l15) * 32 + quad * 8];
#pragma unroll
        for (int nt = 0; nt < 4; nt++)
            bf[nt] = *(const s16x8*)&Bs[(wn * 64 + nt * 16 + l15) * 32 + quad * 8];
#pragma unroll
        for (int mt = 0; mt < 4; mt++)
#pragma unroll
            for (int nt = 0; nt < 4; nt++)
                acc[mt][nt] = __builtin_amdgcn_mfma_f32_16x16x32_bf16(
                    af[mt], bf[nt], acc[mt][nt], 0, 0, 0);
    }

#pragma unroll
    for (int nt = 0; nt < 4; nt++) {
        int n = col0 + wn * 64 + nt * 16 + l15;
        float bv = bias[n];
        if (mode == 1) {
            int seg = n >> 10;
            int nn = n & (E_ - 1);
#pragma unroll
            for (int mt = 0; mt < 4; mt++)
#pragma unroll
                for (int r = 0; r < 4; r++) {
                    int row = row0 + wm * 64 + mt * 16 + quad * 4 + r;
                    float v = acc[mt][nt][r] + bv;
                    size_t idx = (size_t)row * E_ + nn;
                    if (seg == 0)      Qbf[idx] = f2bf(v);
                    else if (seg == 1) { Kf32[idx] = v; Kbf[idx] = f2bf(v); }
                    else               Vf32[idx] = v;
                }
        } else {
#pragma unroll
            for (int mt = 0; mt < 4; mt++)
#pragma unroll
                for (int r = 0; r < 4; r++) {
                    int row = row0 + wm * 64 + mt * 16 + quad * 4 + r;
                    C0[(size_t)row * N + n] = acc[mt][nt][r] + bv;
                }
        }
    }
}

// ---------------------------------------------------------------------------
// V transpose: fp32 V [b*S+s][h*64+d] -> bf16 Vt [(b*H+h)*64+d][s]
// ---------------------------------------------------------------------------
__global__ __launch_bounds__(256) void vtrans_kernel(
    const float* __restrict__ V, ushort* __restrict__ Vt)
{
    __shared__ float tile[64][65];
    int blk = blockIdx.x;
    int s0 = (blk & 31) * 64;
    int bh = blk >> 5;
    int b = bh >> 4, h = bh & 15;
    int tid = threadIdx.x;
    int d = tid & 63;
#pragma unroll
    for (int i = tid >> 6; i < 64; i += 4)
        tile[i][d] = V[((size_t)(b * S_ + s0 + i)) * E_ + h * 64 + d];
    __syncthreads();
    int lane = tid & 63, w = tid >> 6;
#pragma unroll
    for (int dd = w; dd < 64; dd += 4)
        Vt[((size_t)(bh * 64 + dd)) * S_ + s0 + lane] = f2bf(tile[lane][dd]);
}

// ---------------------------------------------------------------------------
// MFMA flash attention, fixed-reference softmax.
// Round-6 change: 512-thread blocks (8 waves). Wave (qslice, par) handles
// q-rows [qt*64 + qslice*16 .. +16) and key tiles t with t%2 == par.
// Fixed-reference softmax (no running max) makes the key-split merge a pure
// add of partial O and partial lsum, done once per q-tile through LDS.
// Balance is preserved exactly: every block runs
// ceil((32-pr)/2) + ceil((pr+1)/2) == 17 staged iterations for any pr.
// Occupancy: 2 blocks/CU (LDS 55KB) -> 16 waves/CU, double the old 8, and
// half the barrier waits per wave. Register prefetch of next K/V/bias tiles
// is retained. Merge buffers alias dead Ps (O partials) and Ks (lsum
// partials): written after the post-compute barrier, read before the next
// loop-top barrier, so no overlap with staging.
// ---------------------------------------------------------------------------
__global__ __launch_bounds__(512, 4) void attn_mfma_kernel(
    const ushort* __restrict__ Qbf,  // [B*S, E] bf16
    const ushort* __restrict__ Kbf,  // [B*S, E] bf16
    const ushort* __restrict__ Vt,   // [(b*H+h)*64+d][S] bf16
    const float* __restrict__ bias,  // [S,S]
    ushort* __restrict__ Ctx)        // [B*S, E] bf16
{
    __shared__ ushort Ks[2][64][72];
    __shared__ ushort Vs[2][64][72];
    __shared__ ushort Ps[8][16][72];
    // merge scratch, aliased over dead regions at merge time:
    f32x4 (*Om)[4][64]   = (f32x4(*)[4][64])Ps;     // [qslice][dt][lane] 16KB
    float (*Lm)[2][64][4] = (float(*)[2][64][4])Ks; // [qslice][par][lane][r] 8KB

    int blk = blockIdx.x;
    int bh = blk & 31;
    int pr = blk >> 5;               // 0..15
    int b = bh >> 4, h = bh & 15;
    int tid = threadIdx.x;
    int wid = tid >> 6, lane = tid & 63;
    int l15 = lane & 15, quad = lane >> 4;
    int qslice = wid >> 1;           // which 16 q-rows
    int par = wid & 1;               // key-tile parity this wave computes

    // staging role: 512 threads cooperatively stage BOTH parity tiles
    int ts = tid & 255;
    int par_s = tid >> 8;            // which parity tile this thread stages
    int skey = ts >> 2;
    int scol = (ts & 3) * 16;
    const float scale = 0.125f;

    const size_t krow = (size_t)(b * S_ + skey) * E_ + h * 64 + scol; // + j0*E_
    const size_t vrow = (size_t)(bh * 64 + skey) * S_ + scol;         // + j0

    for (int half = 0; half < 2; half++) {
        int qt = half ? pr : (31 - pr);
        int q0w = qt * 64 + qslice * 16;
        int U = (qt + 2) >> 1;       // ceil((qt+1)/2) staged iterations

        // Q fragments (A-layout) — both parity waves of a qslice load the same
        const size_t qbase = ((size_t)(b * S_ + q0w + l15)) * E_ + h * 64 + quad * 8;
        s16x8 qa0 = *(const s16x8*)&Qbf[qbase];
        s16x8 qa1 = *(const s16x8*)&Qbf[qbase + 32];

        f32x4 o[4];
#pragma unroll
        for (int dt = 0; dt < 4; dt++) o[dt] = (f32x4){0.f, 0.f, 0.f, 0.f};
        float lsum[4];
#pragma unroll
        for (int r = 0; r < 4; r++) lsum[r] = 0.f;

        // ---- preload staging tile for u=0 (tile par_s, clamped)
        int t0 = (par_s <= qt) ? par_s : qt;
        size_t koff = krow + (size_t)(t0 * 64) * E_;
        size_t voff = vrow + (size_t)(t0 * 64);
        float4 kr0 = ((const float4*)&Kbf[koff])[0];
        float4 kr1 = ((const float4*)&Kbf[koff])[1];
        float4 vr0 = ((const float4*)&Vt[voff])[0];
        float4 vr1 = ((const float4*)&Vt[voff])[1];

        // ---- preload bias for this wave's first tile (t = par), if valid
        float bvn[4][4];
#pragma unroll
        for (int r = 0; r < 4; r++)
#pragma unroll
            for (int kt = 0; kt < 4; kt++) bvn[r][kt] = 0.f;
        if (par <= qt) {
#pragma unroll
            for (int r = 0; r < 4; r++)
#pragma unroll
                for (int kt = 0; kt < 4; kt++)
                    bvn[r][kt] = bias[(size_t)(q0w + quad * 4 + r) * S_
                                      + par * 64 + kt * 16 + l15];
        }

        for (int u = 0; u < U; u++) {
            int tw = 2 * u + par;    // this wave's compute tile
            __syncthreads();          // prior compute done; LDS free
            *(float4*)&Ks[par_s][skey][scol]     = kr0;
            *(float4*)&Ks[par_s][skey][scol + 8] = kr1;
            *(float4*)&Vs[par_s][skey][scol]     = vr0;
            *(float4*)&Vs[par_s][skey][scol + 8] = vr1;
            float bv[4][4];
#pragma unroll
            for (int r = 0; r < 4; r++)
#pragma unroll
                for (int kt = 0; kt < 4; kt++) bv[r][kt] = bvn[r][kt];
            __syncthreads();

            // ---- prefetch iteration u+1 (registers only; hides under compute)
            if (u + 1 < U) {
                int tn = 2 * (u + 1) + par_s;
                if (tn > qt) tn = qt;
                koff = krow + (size_t)(tn * 64) * E_;
                voff = vrow + (size_t)(tn * 64);
                kr0 = ((const float4*)&Kbf[koff])[0];
                kr1 = ((const float4*)&Kbf[koff])[1];
                vr0 = ((const float4*)&Vt[voff])[0];
                vr1 = ((const float4*)&Vt[voff])[1];
                int twn = 2 * (u + 1) + par;
                if (twn <= qt) {
#pragma unroll
                    for (int r = 0; r < 4; r++)
#pragma unroll
                        for (int kt = 0; kt < 4; kt++)
                            bvn[r][kt] = bias[(size_t)(q0w + quad * 4 + r) * S_
                                              + twn * 64 + kt * 16 + l15];
                }
            }

            if (tw <= qt) {
                int j0 = tw * 64;
                // ---- S = Q K^T : rows=q(quad*4+r), cols=key(kt*16+l15)
                f32x4 s[4];
#pragma unroll
                for (int kt = 0; kt < 4; kt++) {
                    s16x8 kb0 = *(const s16x8*)&Ks[par][kt * 16 + l15][quad * 8];
                    s16x8 kb1 = *(const s16x8*)&Ks[par][kt * 16 + l15][quad * 8 + 32];
                    f32x4 acc = (f32x4){0.f, 0.f, 0.f, 0.f};
                    acc = __builtin_amdgcn_mfma_f32_16x16x32_bf16(qa0, kb0, acc, 0, 0, 0);
                    acc = __builtin_amdgcn_mfma_f32_16x16x32_bf16(qa1, kb1, acc, 0, 0, 0);
                    s[kt] = acc;
                }

                // ---- p = exp(s*scale + bias); causal mask -> 0; XOR-swizzled P
                bool diag = (tw == qt);
#pragma unroll
                for (int r = 0; r < 4; r++) {
                    int row = q0w + quad * 4 + r;
#pragma unroll
                    for (int kt = 0; kt < 4; kt++) {
                        int j = j0 + kt * 16 + l15;
                        float v = s[kt][r] * scale + bv[r][kt];
                        float p = (diag && j > row) ? 0.f : __expf(v);
                        lsum[r] += p;
                        int chunk = (kt * 2 + (l15 >> 3)) ^ quad;
                        Ps[wid][quad * 4 + r][chunk * 8 + (l15 & 7)] = f2bf(p);
                    }
                }

                // ---- O += P V  (Ps wave-private: no barrier)
                int cb = (quad ^ (l15 >> 2)) * 8;
                s16x8 pa0 = *(const s16x8*)&Ps[wid][l15][cb];
                s16x8 pa1 = *(const s16x8*)&Ps[wid][l15][cb + 32];
#pragma unroll
                for (int dt = 0; dt < 4; dt++) {
                    s16x8 vb0 = *(const s16x8*)&Vs[par][dt * 16 + l15][quad * 8];
                    s16x8 vb1 = *(const s16x8*)&Vs[par][dt * 16 + l15][quad * 8 + 32];
                    o[dt] = __builtin_amdgcn_mfma_f32_16x16x32_bf16(pa0, vb0, o[dt], 0, 0, 0);
                    o[dt] = __builtin_amdgcn_mfma_f32_16x16x32_bf16(pa1, vb1, o[dt], 0, 0, 0);
                }
            }
        }

        // ---- merge key-parity partials (pure add: fixed-reference softmax)
        // Each wave parks the two dt-quadrants it does NOT own, plus its lsum
        // partial; reads the partner's; each wave stores its 2 owned quadrants.
        __syncthreads();
#pragma unroll
        for (int dt = 0; dt < 4; dt++)
            if ((dt >> 1) != par) Om[qslice][dt][lane] = o[dt];
#pragma unroll
        for (int r = 0; r < 4; r++) Lm[qslice][par][lane][r] = lsum[r];
        __syncthreads();

        float inv_l[4];
#pragma unroll
        for (int r = 0; r < 4; r++) {
            float l = lsum[r] + Lm[qslice][par ^ 1][lane][r];
            l += __shfl_xor(l, 1);
            l += __shfl_xor(l, 2);
            l += __shfl_xor(l, 4);
            l += __shfl_xor(l, 8);
            inv_l[r] = 1.f / l;
        }

#pragma unroll
        for (int dt = 0; dt < 4; dt++) {
            if ((dt >> 1) != par) continue;      // owned quadrants only
            f32x4 pv = Om[qslice][dt][lane];
#pragma unroll
            for (int r = 0; r < 4; r++) {
                int row = q0w + quad * 4 + r;
                Ctx[((size_t)(b * S_ + row)) * E_ + h * 64 + dt * 16 + l15] =
                    f2bf((o[dt][r] + pv[r]) * inv_l[r]);
            }
        }
    }
}

// ---------------------------------------------------------------------------
extern "C" void kernel_launch(void* const* d_in, const int* in_sizes, int n_in,
                              void* d_out, int out_size, void* d_ws, size_t ws_size,
                              hipStream_t stream) {
    const float* X     = (const float*)d_in[0];
    const float* abias = (const float*)d_in[1];
    const float* Wqkv  = (const float*)d_in[2];
    const float* bqkv  = (const float*)d_in[3];
    const float* Wproj = (const float*)d_in[4];
    const float* bproj = (const float*)d_in[5];

    const size_t plane = (size_t)B_ * S_ * E_;   // 4,194,304
    float* out  = (float*)d_out;
    float* kout = out + plane;                   // cache_key (fp32 output)
    float* vout = kout + plane;                  // cache_value (fp32 output)

    // workspace: 4 bf16 planes + weights = 42 MB (proven footprint).
    // ctxbf ALIASES xbf (X's bf16 copy is dead after the QKV GEMM).
    ushort* xbf    = (ushort*)d_ws;
    ushort* qbf    = xbf + plane;
    ushort* kbf    = qbf + plane;
    ushort* vt     = kbf + plane;
    ushort* ctxbf  = xbf;                        // alias (see above)
    ushort* wqkvt  = vt + plane;                 // [3E][E]
    ushort* wprojt = wqkvt + (size_t)3 * E_ * E_;// [E][E]

    const int M = B_ * S_;

    cvtx_kernel<<<dim3(plane / 1024), 256, 0, stream>>>(X, xbf);
    wtrans_kernel<<<dim3(3 * E_ / 64, E_ / 64), 256, 0, stream>>>(Wqkv, wqkvt, E_, 3 * E_);
    wtrans_kernel<<<dim3(E_ / 64, E_ / 64), 256, 0, stream>>>(Wproj, wprojt, E_, E_);

    gemm_mfma_bt<<<dim3(3 * E_ / 128, M / 128), 256, 0, stream>>>(
        xbf, wqkvt, bqkv, M, 3 * E_, E_,
        nullptr, qbf, kout, kbf, vout, 1);

    vtrans_kernel<<<dim3(B_ * H_ * (S_ / 64)), 256, 0, stream>>>(vout, vt);

    // flash attention: 512 blocks x 8 waves, key-parity split inside block
    attn_mfma_kernel<<<dim3(B_ * H_ * 16), 512, 0, stream>>>(
        qbf, kbf, vt, abias, ctxbf);

    gemm_mfma_bt<<<dim3(E_ / 128, M / 128), 256, 0, stream>>>(
        ctxbf, wprojt, bproj, M, E_, E_,
        out, nullptr, nullptr, nullptr, nullptr, 0);
}

// Round 2
// 239.246 us; speedup vs baseline: 1.0784x; 1.0784x over previous
//
#include <hip/hip_runtime.h>

#define B_ 2
#define S_ 2048
#define E_ 1024
#define H_ 16
#define D_ 64

typedef short  s16x8 __attribute__((ext_vector_type(8)));
typedef float  f32x4 __attribute__((ext_vector_type(4)));
typedef unsigned short u16x4 __attribute__((ext_vector_type(4)));

__device__ __forceinline__ ushort f2bf(float f) {
    union { float f; unsigned u; } x; x.f = f;
    unsigned u = x.u + 0x7fffu + ((x.u >> 16) & 1u);   // RNE
    return (ushort)(u >> 16);
}

// ---------------------------------------------------------------------------
// X fp32 -> bf16 (flat, 4 elems/thread)
// ---------------------------------------------------------------------------
__global__ __launch_bounds__(256) void cvtx_kernel(
    const float* __restrict__ X, ushort* __restrict__ Xbf)
{
    int i = (blockIdx.x * 256 + threadIdx.x) * 4;
    float4 v = *(const float4*)&X[i];
    u16x4 o;
    o.x = f2bf(v.x); o.y = f2bf(v.y); o.z = f2bf(v.z); o.w = f2bf(v.w);
    *(u16x4*)&Xbf[i] = o;
}

// ---------------------------------------------------------------------------
// W fp32 [Kdim][Ndim] -> Wt bf16 [Ndim][Kdim]  (64x64 LDS tiles)
// ---------------------------------------------------------------------------
__global__ __launch_bounds__(256) void wtrans_kernel(
    const float* __restrict__ W, ushort* __restrict__ Wt, int Kdim, int Ndim)
{
    __shared__ float tile[64][65];
    int n0 = blockIdx.x * 64, k0 = blockIdx.y * 64;
    int tid = threadIdx.x;
    int c = tid & 63;
#pragma unroll
    for (int r = tid >> 6; r < 64; r += 4)
        tile[r][c] = W[(size_t)(k0 + r) * Ndim + n0 + c];
    __syncthreads();
#pragma unroll
    for (int r = tid >> 6; r < 64; r += 4)
        Wt[(size_t)(n0 + r) * Kdim + k0 + c] = f2bf(tile[c][r]);
}

// ---------------------------------------------------------------------------
// bf16 MFMA GEMM (m97 structure): C[m][n] = sum_k A[m][k]*Bt[n][k] + bias[n]
// 128x128 tile, BK=32, global_load_lds w=16, ds_read_b128 frags.
// mode 0: fp32 C0. mode 1 (N=3E): seg0->Qbf, seg1->Kf32+Kbf, seg2->Vf32.
// ---------------------------------------------------------------------------
__global__ __launch_bounds__(256) void gemm_mfma_bt(
    const ushort* __restrict__ A,    // [M][K] bf16
    const ushort* __restrict__ Bt,   // [N][K] bf16
    const float* __restrict__ bias,  // [N]
    int M, int N, int K,
    float* __restrict__ C0,
    ushort* __restrict__ Qbf, float* __restrict__ Kf32, ushort* __restrict__ Kbf,
    float* __restrict__ Vf32, int mode)
{
    __shared__ ushort As[128 * 32];
    __shared__ ushort Bs[128 * 32];
    int tid = threadIdx.x;
    int wid = tid >> 6, lane = tid & 63;
    int l15 = lane & 15, quad = lane >> 4;
    int wm = wid >> 1, wn = wid & 1;
    int row0 = blockIdx.y * 128, col0 = blockIdx.x * 128;

    int sr = wid * 16 + (lane >> 2);
    int sk = (lane & 3) * 8;

    f32x4 acc[4][4];
#pragma unroll
    for (int mt = 0; mt < 4; mt++)
#pragma unroll
        for (int nt = 0; nt < 4; nt++) acc[mt][nt] = (f32x4){0.f, 0.f, 0.f, 0.f};

    for (int k0 = 0; k0 < K; k0 += 32) {
        __syncthreads();
#pragma unroll
        for (int c = 0; c < 2; c++) {
            int r = c * 64 + sr;
            __builtin_amdgcn_global_load_lds(
                (const __attribute__((address_space(1))) unsigned int*)
                    &A[(size_t)(row0 + r) * K + k0 + sk],
                (__attribute__((address_space(3))) unsigned int*)&As[r * 32 + sk],
                16, 0, 0);
            __builtin_amdgcn_global_load_lds(
                (const __attribute__((address_space(1))) unsigned int*)
                    &Bt[(size_t)(col0 + r) * K + k0 + sk],
                (__attribute__((address_space(3))) unsigned int*)&Bs[r * 32 + sk],
                16, 0, 0);
        }
        __syncthreads();

        s16x8 af[4], bf[4];
#pragma unroll
        for (int mt = 0; mt < 4; mt++)
            af[mt] = *(const s16x8*)&As[(wm * 64 + mt * 16 + l15) * 32 + quad * 8];
#pragma unroll
        for (int nt = 0; nt < 4; nt++)
            bf[nt] = *(const s16x8*)&Bs[(wn * 64 + nt * 16 + l15) * 32 + quad * 8];
#pragma unroll
        for (int mt = 0; mt < 4; mt++)
#pragma unroll
            for (int nt = 0; nt < 4; nt++)
                acc[mt][nt] = __builtin_amdgcn_mfma_f32_16x16x32_bf16(
                    af[mt], bf[nt], acc[mt][nt], 0, 0, 0);
    }

#pragma unroll
    for (int nt = 0; nt < 4; nt++) {
        int n = col0 + wn * 64 + nt * 16 + l15;
        float bv = bias[n];
        if (mode == 1) {
            int seg = n >> 10;
            int nn = n & (E_ - 1);
#pragma unroll
            for (int mt = 0; mt < 4; mt++)
#pragma unroll
                for (int r = 0; r < 4; r++) {
                    int row = row0 + wm * 64 + mt * 16 + quad * 4 + r;
                    float v = acc[mt][nt][r] + bv;
                    size_t idx = (size_t)row * E_ + nn;
                    if (seg == 0)      Qbf[idx] = f2bf(v);
                    else if (seg == 1) { Kf32[idx] = v; Kbf[idx] = f2bf(v); }
                    else               Vf32[idx] = v;
                }
        } else {
#pragma unroll
            for (int mt = 0; mt < 4; mt++)
#pragma unroll
                for (int r = 0; r < 4; r++) {
                    int row = row0 + wm * 64 + mt * 16 + quad * 4 + r;
                    C0[(size_t)row * N + n] = acc[mt][nt][r] + bv;
                }
        }
    }
}

// ---------------------------------------------------------------------------
// V transpose: fp32 V [b*S+s][h*64+d] -> bf16 Vt [(b*H+h)*64+d][s]
// ---------------------------------------------------------------------------
__global__ __launch_bounds__(256) void vtrans_kernel(
    const float* __restrict__ V, ushort* __restrict__ Vt)
{
    __shared__ float tile[64][65];
    int blk = blockIdx.x;
    int s0 = (blk & 31) * 64;
    int bh = blk >> 5;
    int b = bh >> 4, h = bh & 15;
    int tid = threadIdx.x;
    int d = tid & 63;
#pragma unroll
    for (int i = tid >> 6; i < 64; i += 4)
        tile[i][d] = V[((size_t)(b * S_ + s0 + i)) * E_ + h * 64 + d];
    __syncthreads();
    int lane = tid & 63, w = tid >> 6;
#pragma unroll
    for (int dd = w; dd < 64; dd += 4)
        Vt[((size_t)(bh * 64 + dd)) * S_ + s0 + lane] = f2bf(tile[lane][dd]);
}

// ---------------------------------------------------------------------------
// MFMA flash attention, fixed-reference softmax.
// Round-7 change: back to the proven 256-thread / 4-wave inner loop (round-1's
// 512-thread variant spilled: VGPR forced 84->64, +46MB scratch HBM traffic).
// Concurrency now comes from DECOMPOSITION: 1024 blocks, one q-tile each
// (was 512 blocks x 2 q-tiles). Resource check: VGPR 84 -> 6 waves/SIMD cap,
// LDS 27.6KB -> 5 blocks/CU cap; grid 1024 = 4 blocks/CU average, so
// ~16-20 resident waves/CU vs 8 before. Blocks are ordered largest-qt-first
// (LPT): qt = 31 - (blk>>5), so the 32-unit blocks start first and the tail
// is filled by small ones under dynamic dispatch.
// Pipelining: K/V/bias for tile t+1 prefetched into registers (unchanged).
// P tile: XOR-swizzled 8-ushort chunks (unchanged).
// ---------------------------------------------------------------------------
__global__ __launch_bounds__(256) void attn_mfma_kernel(
    const ushort* __restrict__ Qbf,  // [B*S, E] bf16
    const ushort* __restrict__ Kbf,  // [B*S, E] bf16
    const ushort* __restrict__ Vt,   // [(b*H+h)*64+d][S] bf16
    const float* __restrict__ bias,  // [S,S]
    ushort* __restrict__ Ctx)        // [B*S, E] bf16
{
    __shared__ ushort Ks[64][72];
    __shared__ ushort Vs[64][72];
    __shared__ ushort Ps[4][16][72];

    int blk = blockIdx.x;
    int bh = blk & 31;
    int qt = 31 - (blk >> 5);        // largest q-tiles dispatched first (LPT)
    int b = bh >> 4, h = bh & 15;
    int tid = threadIdx.x;
    int wid = tid >> 6, lane = tid & 63;
    int l15 = lane & 15, quad = lane >> 4;

    int skey = tid >> 2;
    int scol = (tid & 3) * 16;
    const float scale = 0.125f;

    const size_t krow = (size_t)(b * S_ + skey) * E_ + h * 64 + scol; // + j0*E_
    const size_t vrow = (size_t)(bh * 64 + skey) * S_ + scol;        // + j0

    int q0w = qt * 64 + wid * 16;

    // Q fragments (A-layout)
    const size_t qbase = ((size_t)(b * S_ + q0w + l15)) * E_ + h * 64 + quad * 8;
    s16x8 qa0 = *(const s16x8*)&Qbf[qbase];
    s16x8 qa1 = *(const s16x8*)&Qbf[qbase + 32];

    f32x4 o[4];
#pragma unroll
    for (int dt = 0; dt < 4; dt++) o[dt] = (f32x4){0.f, 0.f, 0.f, 0.f};
    float lsum[4];
#pragma unroll
    for (int r = 0; r < 4; r++) lsum[r] = 0.f;

    // ---- preload tile 0 into registers
    float4 kr0 = ((const float4*)&Kbf[krow])[0];
    float4 kr1 = ((const float4*)&Kbf[krow])[1];
    float4 vr0 = ((const float4*)&Vt[vrow])[0];
    float4 vr1 = ((const float4*)&Vt[vrow])[1];
    float bvn[4][4];
#pragma unroll
    for (int r = 0; r < 4; r++)
#pragma unroll
        for (int kt = 0; kt < 4; kt++)
            bvn[r][kt] = bias[(size_t)(q0w + quad * 4 + r) * S_ + kt * 16 + l15];

    for (int t = 0; t <= qt; t++) {
        int j0 = t * 64;
        __syncthreads();          // prior compute done; LDS free
        *(float4*)&Ks[skey][scol]     = kr0;
        *(float4*)&Ks[skey][scol + 8] = kr1;
        *(float4*)&Vs[skey][scol]     = vr0;
        *(float4*)&Vs[skey][scol + 8] = vr1;
        float bv[4][4];
#pragma unroll
        for (int r = 0; r < 4; r++)
#pragma unroll
            for (int kt = 0; kt < 4; kt++) bv[r][kt] = bvn[r][kt];
        __syncthreads();

        // ---- prefetch tile t+1 (registers only; hides under compute)
        if (t < qt) {
            int j1 = j0 + 64;
            kr0 = ((const float4*)&Kbf[krow + (size_t)j1 * E_])[0];
            kr1 = ((const float4*)&Kbf[krow + (size_t)j1 * E_])[1];
            vr0 = ((const float4*)&Vt[vrow + j1])[0];
            vr1 = ((const float4*)&Vt[vrow + j1])[1];
#pragma unroll
            for (int r = 0; r < 4; r++)
#pragma unroll
                for (int kt = 0; kt < 4; kt++)
                    bvn[r][kt] = bias[(size_t)(q0w + quad * 4 + r) * S_ + j1 + kt * 16 + l15];
        }

        // ---- S = Q K^T : rows=q(quad*4+r), cols=key(kt*16+l15)
        f32x4 s[4];
#pragma unroll
        for (int kt = 0; kt < 4; kt++) {
            s16x8 kb0 = *(const s16x8*)&Ks[kt * 16 + l15][quad * 8];
            s16x8 kb1 = *(const s16x8*)&Ks[kt * 16 + l15][quad * 8 + 32];
            f32x4 acc = (f32x4){0.f, 0.f, 0.f, 0.f};
            acc = __builtin_amdgcn_mfma_f32_16x16x32_bf16(qa0, kb0, acc, 0, 0, 0);
            acc = __builtin_amdgcn_mfma_f32_16x16x32_bf16(qa1, kb1, acc, 0, 0, 0);
            s[kt] = acc;
        }

        // ---- p = exp(s*scale + bias); causal mask -> 0; XOR-swizzled P
        bool diag = (t == qt);
#pragma unroll
        for (int r = 0; r < 4; r++) {
            int row = q0w + quad * 4 + r;
#pragma unroll
            for (int kt = 0; kt < 4; kt++) {
                int j = j0 + kt * 16 + l15;
                float v = s[kt][r] * scale + bv[r][kt];
                float p = (diag && j > row) ? 0.f : __expf(v);
                lsum[r] += p;
                int chunk = (kt * 2 + (l15 >> 3)) ^ quad;
                Ps[wid][quad * 4 + r][chunk * 8 + (l15 & 7)] = f2bf(p);
            }
        }

        // ---- O += P V  (Ps wave-private: no barrier)
        int cb = (quad ^ (l15 >> 2)) * 8;
        s16x8 pa0 = *(const s16x8*)&Ps[wid][l15][cb];
        s16x8 pa1 = *(const s16x8*)&Ps[wid][l15][cb + 32];
#pragma unroll
        for (int dt = 0; dt < 4; dt++) {
            s16x8 vb0 = *(const s16x8*)&Vs[dt * 16 + l15][quad * 8];
            s16x8 vb1 = *(const s16x8*)&Vs[dt * 16 + l15][quad * 8 + 32];
            o[dt] = __builtin_amdgcn_mfma_f32_16x16x32_bf16(pa0, vb0, o[dt], 0, 0, 0);
            o[dt] = __builtin_amdgcn_mfma_f32_16x16x32_bf16(pa1, vb1, o[dt], 0, 0, 0);
        }
    }

    // ---- single final row-sum reduction
    float inv_l[4];
#pragma unroll
    for (int r = 0; r < 4; r++) {
        float l = lsum[r];
        l += __shfl_xor(l, 1);
        l += __shfl_xor(l, 2);
        l += __shfl_xor(l, 4);
        l += __shfl_xor(l, 8);
        inv_l[r] = 1.f / l;
    }

#pragma unroll
    for (int dt = 0; dt < 4; dt++) {
#pragma unroll
        for (int r = 0; r < 4; r++) {
            int row = q0w + quad * 4 + r;
            Ctx[((size_t)(b * S_ + row)) * E_ + h * 64 + dt * 16 + l15] =
                f2bf(o[dt][r] * inv_l[r]);
        }
    }
}

// ---------------------------------------------------------------------------
extern "C" void kernel_launch(void* const* d_in, const int* in_sizes, int n_in,
                              void* d_out, int out_size, void* d_ws, size_t ws_size,
                              hipStream_t stream) {
    const float* X     = (const float*)d_in[0];
    const float* abias = (const float*)d_in[1];
    const float* Wqkv  = (const float*)d_in[2];
    const float* bqkv  = (const float*)d_in[3];
    const float* Wproj = (const float*)d_in[4];
    const float* bproj = (const float*)d_in[5];

    const size_t plane = (size_t)B_ * S_ * E_;   // 4,194,304
    float* out  = (float*)d_out;
    float* kout = out + plane;                   // cache_key (fp32 output)
    float* vout = kout + plane;                  // cache_value (fp32 output)

    // workspace: 4 bf16 planes + weights = 42 MB (proven footprint).
    // ctxbf ALIASES xbf (X's bf16 copy is dead after the QKV GEMM).
    ushort* xbf    = (ushort*)d_ws;
    ushort* qbf    = xbf + plane;
    ushort* kbf    = qbf + plane;
    ushort* vt     = kbf + plane;
    ushort* ctxbf  = xbf;                        // alias (see above)
    ushort* wqkvt  = vt + plane;                 // [3E][E]
    ushort* wprojt = wqkvt + (size_t)3 * E_ * E_;// [E][E]

    const int M = B_ * S_;

    cvtx_kernel<<<dim3(plane / 1024), 256, 0, stream>>>(X, xbf);
    wtrans_kernel<<<dim3(3 * E_ / 64, E_ / 64), 256, 0, stream>>>(Wqkv, wqkvt, E_, 3 * E_);
    wtrans_kernel<<<dim3(E_ / 64, E_ / 64), 256, 0, stream>>>(Wproj, wprojt, E_, E_);

    gemm_mfma_bt<<<dim3(3 * E_ / 128, M / 128), 256, 0, stream>>>(
        xbf, wqkvt, bqkv, M, 3 * E_, E_,
        nullptr, qbf, kout, kbf, vout, 1);

    vtrans_kernel<<<dim3(B_ * H_ * (S_ / 64)), 256, 0, stream>>>(vout, vt);

    // flash attention: 1024 blocks, one q-tile each, largest-first (LPT)
    attn_mfma_kernel<<<dim3(B_ * H_ * 32), 256, 0, stream>>>(
        qbf, kbf, vt, abias, ctxbf);

    gemm_mfma_bt<<<dim3(E_ / 128, M / 128), 256, 0, stream>>>(
        ctxbf, wprojt, bproj, M, E_, E_,
        out, nullptr, nullptr, nullptr, nullptr, 0);
}